// Round 1
// baseline (287.128 us; speedup 1.0000x reference)
//
#include <hip/hip_runtime.h>
#include <hip/hip_bf16.h>
#include <stdint.h>

// ---------- problem constants ----------
#define NB    16384     // batch
#define NCONT 13
#define NF    26
#define NV    100000
#define ND    16
#define NH    400       // H1 == H2
#define K1    448       // padded DNN_IN: [E(416) | cont(13) | pad(19)]
#define K2    416       // padded H1 (400 -> 416)
#define NPAD  512       // padded N for 128-wide tiles

typedef __attribute__((ext_vector_type(8))) __bf16 bf16x8;
typedef __attribute__((ext_vector_type(8))) short short8;
typedef __attribute__((ext_vector_type(4))) float f32x4;

__device__ __forceinline__ short f2bf(float x) {
  union { float f; uint32_t u; } c; c.f = x;
  uint32_t r = (c.u + 0x7FFFu + ((c.u >> 16) & 1u)) >> 16;   // RNE
  return (short)(uint16_t)r;
}

__device__ __forceinline__ void load16(const void* g, void* l) {
  __builtin_amdgcn_global_load_lds(
      (const __attribute__((address_space(1))) void*)g,
      (__attribute__((address_space(3))) void*)l, 16, 0, 0);
}

// ---------- weight prep: transpose + pad + bf16 ----------
__global__ __launch_bounds__(256)
void prep_k(const float* __restrict__ W1, const float* __restrict__ W2,
            short* __restrict__ W1T, short* __restrict__ W2T) {
  int t = blockIdx.x * 256 + threadIdx.x;
  if (t < NPAD * K1) {
    int n = t / K1, k = t - n * K1;
    float v = 0.f;
    if (n < NH) {
      if (k < 416)       v = W1[(size_t)(13 + k) * NH + n];   // E part
      else if (k < 429)  v = W1[(size_t)(k - 416) * NH + n];  // cont part
    }
    W1T[t] = f2bf(v);
  } else {
    int u = t - NPAD * K1;           // grid sized exactly, u < NPAD*K2
    int n = u / K2, k = u - n * K2;
    float v = (n < NH && k < NH) ? W2[(size_t)k * NH + n] : 0.f;
    W2T[u] = f2bf(v);
  }
}

// ---------- gather + FM path + dnn_in pack (4 threads per row) ----------
__global__ __launch_bounds__(256)
void gather_k(const float* __restrict__ cont, const int* __restrict__ cat,
              const float* __restrict__ Wc, const float* __restrict__ bc,
              const float* __restrict__ emb1, const float* __restrict__ emb,
              const float* __restrict__ Wout, const float* __restrict__ bout,
              short* __restrict__ dnn, float* __restrict__ out) {
  int t = blockIdx.x * 256 + threadIdx.x;
  int b = t >> 2;
  int q = t & 3;
  int f0 = (26 * q) >> 2;        // 0,6,13,19
  int f1 = (26 * (q + 1)) >> 2;  // 6,13,19,26
  float se[16];
#pragma unroll
  for (int d = 0; d < 16; d++) se[d] = 0.f;
  float sumsq = 0.f, fm1 = 0.f;
  short* drow = dnn + (size_t)b * K1;

  for (int f = f0; f < f1; f++) {
    int idx = cat[b * NF + f];
    const float4* ep = (const float4*)(emb + ((size_t)f * NV + idx) * ND);
    float4 e0 = ep[0], e1 = ep[1], e2 = ep[2], e3 = ep[3];
    fm1 += emb1[(size_t)f * NV + idx];
    se[0] += e0.x; se[1] += e0.y; se[2] += e0.z; se[3] += e0.w;
    se[4] += e1.x; se[5] += e1.y; se[6] += e1.z; se[7] += e1.w;
    se[8] += e2.x; se[9] += e2.y; se[10] += e2.z; se[11] += e2.w;
    se[12] += e3.x; se[13] += e3.y; se[14] += e3.z; se[15] += e3.w;
    sumsq += e0.x*e0.x + e0.y*e0.y + e0.z*e0.z + e0.w*e0.w
           + e1.x*e1.x + e1.y*e1.y + e1.z*e1.z + e1.w*e1.w
           + e2.x*e2.x + e2.y*e2.y + e2.z*e2.z + e2.w*e2.w
           + e3.x*e3.x + e3.y*e3.y + e3.z*e3.z + e3.w*e3.w;
    short8 p0, p1;
    p0[0]=f2bf(e0.x); p0[1]=f2bf(e0.y); p0[2]=f2bf(e0.z); p0[3]=f2bf(e0.w);
    p0[4]=f2bf(e1.x); p0[5]=f2bf(e1.y); p0[6]=f2bf(e1.z); p0[7]=f2bf(e1.w);
    p1[0]=f2bf(e2.x); p1[1]=f2bf(e2.y); p1[2]=f2bf(e2.z); p1[3]=f2bf(e2.w);
    p1[4]=f2bf(e3.x); p1[5]=f2bf(e3.y); p1[6]=f2bf(e3.z); p1[7]=f2bf(e3.w);
    *(short8*)(drow + f * 16) = p0;
    *(short8*)(drow + f * 16 + 8) = p1;
  }
  // combine the 4 lanes of this row (lanes differ in bits 0..1)
#pragma unroll
  for (int d = 0; d < 16; d++) {
    se[d] += __shfl_xor(se[d], 1, 64);
    se[d] += __shfl_xor(se[d], 2, 64);
  }
  sumsq += __shfl_xor(sumsq, 1, 64);
  sumsq += __shfl_xor(sumsq, 2, 64);
  fm1   += __shfl_xor(fm1, 1, 64);
  fm1   += __shfl_xor(fm1, 2, 64);

  if (q == 0) {
    float s2 = 0.f;
#pragma unroll
    for (int d = 0; d < 16; d++) s2 += se[d] * se[d];
    float fm2 = 0.5f * (s2 - sumsq);
    float fmc = bc[0];
    short tail[32];
#pragma unroll
    for (int i = 0; i < 13; i++) {
      float c = cont[(size_t)b * NCONT + i];
      fmc += c * Wc[i];
      tail[i] = f2bf(c);
    }
#pragma unroll
    for (int i = 13; i < 32; i++) tail[i] = 0;
#pragma unroll
    for (int v2 = 0; v2 < 4; v2++) {
      short8 tv;
#pragma unroll
      for (int e = 0; e < 8; e++) tv[e] = tail[v2 * 8 + e];
      *(short8*)(drow + 416 + v2 * 8) = tv;
    }
    out[b] = (fm1 + fmc + fm2) * Wout[0] + bout[0];
  }
}

// ---------- shared GEMM main loop: C[128x128] += A[128xK] * Bt[128xK]^T ----------
template <int K>
__device__ __forceinline__ void gemm_core(const short* __restrict__ A,
                                          const short* __restrict__ Bt,
                                          short* lA, short* lB,
                                          int bm, int bn, int tid,
                                          f32x4 acc[4][4]) {
  const int lane = tid & 63;
  const int wave = tid >> 6;
  const int wm = (wave & 1) * 64;
  const int wn = (wave >> 1) * 64;
  const int lrow = lane & 15;
  const int quad = lane >> 4;
  // staging: 512 16B segments per tile; thread t covers segs t and t+256
  const int r0 = tid >> 2, s0 = (tid & 3) * 8;
  const short* gA0 = A + (size_t)(bm + r0) * K + s0;
  const short* gA1 = A + (size_t)(bm + r0 + 64) * K + s0;
  const short* gB0 = Bt + (size_t)(bn + r0) * K + s0;
  const short* gB1 = Bt + (size_t)(bn + r0 + 64) * K + s0;
  short* lA0 = lA + tid * 8;
  short* lA1 = lA + (tid + 256) * 8;
  short* lB0 = lB + tid * 8;
  short* lB1 = lB + (tid + 256) * 8;

  for (int k0 = 0; k0 < K; k0 += 32) {
    __syncthreads();
    load16(gA0 + k0, lA0);
    load16(gA1 + k0, lA1);
    load16(gB0 + k0, lB0);
    load16(gB1 + k0, lB1);
    __syncthreads();
    bf16x8 af[4], bfr[4];
#pragma unroll
    for (int i = 0; i < 4; i++)
      af[i] = *(const bf16x8*)(lA + (wm + i * 16 + lrow) * 32 + quad * 8);
#pragma unroll
    for (int j = 0; j < 4; j++)
      bfr[j] = *(const bf16x8*)(lB + (wn + j * 16 + lrow) * 32 + quad * 8);
#pragma unroll
    for (int i = 0; i < 4; i++)
#pragma unroll
      for (int j = 0; j < 4; j++)
        acc[i][j] = __builtin_amdgcn_mfma_f32_16x16x32_bf16(af[i], bfr[j], acc[i][j], 0, 0, 0);
  }
}

// ---------- GEMM1: H = relu(dnn @ W1 + b1), bf16 out, padded to 416 cols ----------
__global__ __launch_bounds__(256, 2)
void gemm1_k(const short* __restrict__ A, const short* __restrict__ Bt,
             const float* __restrict__ b1, short* __restrict__ H) {
  __shared__ short lA[128 * 32];
  __shared__ short lB[128 * 32];
  f32x4 acc[4][4];
#pragma unroll
  for (int i = 0; i < 4; i++)
#pragma unroll
    for (int j = 0; j < 4; j++)
#pragma unroll
      for (int r = 0; r < 4; r++) acc[i][j][r] = 0.f;
  int tid = threadIdx.x;
  int bm = blockIdx.y * 128, bn = blockIdx.x * 128;
  gemm_core<K1>(A, Bt, lA, lB, bm, bn, tid, acc);

  int lane = tid & 63, wave = tid >> 6;
  int wm = (wave & 1) * 64, wn = (wave >> 1) * 64;
  int lrow = lane & 15, quad = lane >> 4;
#pragma unroll
  for (int j = 0; j < 4; j++) {
    int col = bn + wn + j * 16 + lrow;
    if (col >= K2) continue;          // cols 416..511: not stored
    bool pad = (col >= NH);           // cols 400..415: store 0
    float bias = pad ? 0.f : b1[col];
#pragma unroll
    for (int i = 0; i < 4; i++) {
#pragma unroll
      for (int r = 0; r < 4; r++) {
        int row = bm + wm + i * 16 + quad * 4 + r;
        float v = pad ? 0.f : fmaxf(acc[i][j][r] + bias, 0.f);
        H[(size_t)row * K2 + col] = f2bf(v);
      }
    }
  }
}

// ---------- GEMM2: out[b] += sum_n relu(H@W2+b2)[b,n] * Wout[1+n] ----------
__global__ __launch_bounds__(256, 2)
void gemm2_k(const short* __restrict__ A, const short* __restrict__ Bt,
             const float* __restrict__ b2, const float* __restrict__ Wout,
             float* __restrict__ out) {
  __shared__ short lA[128 * 32];
  __shared__ short lB[128 * 32];
  f32x4 acc[4][4];
#pragma unroll
  for (int i = 0; i < 4; i++)
#pragma unroll
    for (int j = 0; j < 4; j++)
#pragma unroll
      for (int r = 0; r < 4; r++) acc[i][j][r] = 0.f;
  int tid = threadIdx.x;
  int bm = blockIdx.y * 128, bn = blockIdx.x * 128;
  gemm_core<K2>(A, Bt, lA, lB, bm, bn, tid, acc);

  int lane = tid & 63, wave = tid >> 6;
  int wm = (wave & 1) * 64, wn = (wave >> 1) * 64;
  int lrow = lane & 15, quad = lane >> 4;
  float bw[4], wo[4];
#pragma unroll
  for (int j = 0; j < 4; j++) {
    int col = bn + wn + j * 16 + lrow;
    bw[j] = (col < NH) ? b2[col] : 0.f;
    wo[j] = (col < NH) ? Wout[1 + col] : 0.f;
  }
#pragma unroll
  for (int i = 0; i < 4; i++) {
#pragma unroll
    for (int r = 0; r < 4; r++) {
      float s = 0.f;
#pragma unroll
      for (int j = 0; j < 4; j++)
        s += fmaxf(acc[i][j][r] + bw[j], 0.f) * wo[j];  // pad cols: acc=0,bw=0,wo=0 -> 0
      s += __shfl_xor(s, 1, 64);
      s += __shfl_xor(s, 2, 64);
      s += __shfl_xor(s, 4, 64);
      s += __shfl_xor(s, 8, 64);
      if (lrow == 0) {
        int row = bm + wm + i * 16 + quad * 4 + r;
        atomicAdd(&out[row], s);
      }
    }
  }
}

extern "C" void kernel_launch(void* const* d_in, const int* in_sizes, int n_in,
                              void* d_out, int out_size, void* d_ws, size_t ws_size,
                              hipStream_t stream) {
  const float* cont   = (const float*)d_in[0];
  const int*   cat    = (const int*)d_in[1];
  const float* W_cont = (const float*)d_in[2];
  const float* b_cont = (const float*)d_in[3];
  const float* emb1   = (const float*)d_in[4];
  const float* emb    = (const float*)d_in[5];
  const float* W1     = (const float*)d_in[6];
  const float* b1     = (const float*)d_in[7];
  const float* W2     = (const float*)d_in[8];
  const float* b2     = (const float*)d_in[9];
  const float* W_out  = (const float*)d_in[10];
  const float* b_out  = (const float*)d_in[11];
  float* out = (float*)d_out;

  char* ws = (char*)d_ws;
  size_t off = 0;
  short* dnn = (short*)(ws + off); off += (size_t)NB * K1 * 2;      // 14.68 MB
  short* W1T = (short*)(ws + off); off += (size_t)NPAD * K1 * 2;    // 0.46 MB
  short* W2T = (short*)(ws + off); off += (size_t)NPAD * K2 * 2;    // 0.43 MB
  short* H   = (short*)(ws + off); off += (size_t)NB * K2 * 2;      // 13.63 MB
  (void)ws_size; (void)in_sizes; (void)n_in; (void)out_size;

  prep_k<<<dim3((NPAD * K1 + NPAD * K2) / 256), dim3(256), 0, stream>>>(W1, W2, W1T, W2T);
  gather_k<<<dim3(NB * 4 / 256), dim3(256), 0, stream>>>(cont, cat, W_cont, b_cont,
                                                         emb1, emb, W_out, b_out, dnn, out);
  gemm1_k<<<dim3(4, NB / 128), dim3(256), 0, stream>>>(dnn, W1T, b1, H);
  gemm2_k<<<dim3(4, NB / 128), dim3(256), 0, stream>>>(H, W2T, b2, W_out, out);
}

// Round 2
// 281.441 us; speedup vs baseline: 1.0202x; 1.0202x over previous
//
#include <hip/hip_runtime.h>
#include <hip/hip_bf16.h>
#include <stdint.h>

// ---------- problem constants ----------
#define NB    16384     // batch
#define NCONT 13
#define NF    26
#define NV    100000
#define ND    16
#define NH    400       // H1 == H2
#define K1    448       // padded DNN_IN: [E(416) | cont(13) | pad(19)]
#define KP1   456       // LDS stride (shorts) for dnn tile: +8 pad -> 2-way banks only
#define K2    416       // padded H1 (400 -> 416)
#define KP2   424       // LDS stride (shorts) for h1 tile
#define NPAD  512       // padded N for 128-wide stripes
#define ROWS  32        // batch rows per block

typedef __attribute__((ext_vector_type(8))) __bf16 bf16x8;
typedef __attribute__((ext_vector_type(8))) short short8;
typedef __attribute__((ext_vector_type(4))) float f32x4;

__device__ __forceinline__ short f2bf(float x) {
  union { float f; uint32_t u; } c; c.f = x;
  uint32_t r = (c.u + 0x7FFFu + ((c.u >> 16) & 1u)) >> 16;   // RNE
  return (short)(uint16_t)r;
}

// ---------- weight prep: transpose + pad + bf16 ----------
__global__ __launch_bounds__(256)
void prep_k(const float* __restrict__ W1, const float* __restrict__ W2,
            short* __restrict__ W1T, short* __restrict__ W2T) {
  int t = blockIdx.x * 256 + threadIdx.x;
  if (t < NPAD * K1) {
    int n = t / K1, k = t - n * K1;
    float v = 0.f;
    if (n < NH) {
      if (k < 416)       v = W1[(size_t)(13 + k) * NH + n];   // E part
      else if (k < 429)  v = W1[(size_t)(k - 416) * NH + n];  // cont part
    }
    W1T[t] = f2bf(v);
  } else {
    int u = t - NPAD * K1;           // grid sized exactly, u < NPAD*K2
    int n = u / K2, k = u - n * K2;
    float v = (n < NH && k < NH) ? W2[(size_t)k * NH + n] : 0.f;
    W2T[u] = f2bf(v);
  }
}

// ---------- fused: gather+FM -> LDS dnn tile -> L1 GEMM -> LDS h1 -> L2 GEMM -> out ----------
__global__ __launch_bounds__(256, 2)
void fused_k(const float* __restrict__ cont, const int* __restrict__ cat,
             const float* __restrict__ Wc, const float* __restrict__ bc,
             const float* __restrict__ emb1, const float* __restrict__ emb,
             const short* __restrict__ W1T, const float* __restrict__ b1,
             const short* __restrict__ W2T, const float* __restrict__ b2,
             const float* __restrict__ Wout, const float* __restrict__ bout,
             float* __restrict__ out) {
  __shared__ short lA[ROWS * KP1];   // dnn tile, bf16 [32][456]
  __shared__ short lH[ROWS * KP2];   // h1 tile,  bf16 [32][424]
  const int tid = threadIdx.x;
  const int bm = blockIdx.x * ROWS;

  // ===== phase 1: embedding gather + FM, build dnn tile in LDS (8 threads/row) =====
  {
    const int q  = tid & 7;
    const int rl = tid >> 3;                 // local row 0..31
    const int b  = bm + rl;
    const int f0 = (NF * q) >> 3;            // 0,3,6,9,13,16,19,22
    const int f1 = (NF * (q + 1)) >> 3;
    float se[16];
#pragma unroll
    for (int d = 0; d < 16; d++) se[d] = 0.f;
    float sumsq = 0.f, fm1 = 0.f;

    for (int f = f0; f < f1; f++) {
      int idx = cat[(size_t)b * NF + f];
      const float4* ep = (const float4*)(emb + ((size_t)f * NV + idx) * ND);
      float4 e0 = ep[0], e1 = ep[1], e2 = ep[2], e3 = ep[3];
      fm1 += emb1[(size_t)f * NV + idx];
      se[0] += e0.x; se[1] += e0.y; se[2] += e0.z; se[3] += e0.w;
      se[4] += e1.x; se[5] += e1.y; se[6] += e1.z; se[7] += e1.w;
      se[8] += e2.x; se[9] += e2.y; se[10] += e2.z; se[11] += e2.w;
      se[12] += e3.x; se[13] += e3.y; se[14] += e3.z; se[15] += e3.w;
      sumsq += e0.x*e0.x + e0.y*e0.y + e0.z*e0.z + e0.w*e0.w
             + e1.x*e1.x + e1.y*e1.y + e1.z*e1.z + e1.w*e1.w
             + e2.x*e2.x + e2.y*e2.y + e2.z*e2.z + e2.w*e2.w
             + e3.x*e3.x + e3.y*e3.y + e3.z*e3.z + e3.w*e3.w;
      short8 p0, p1;
      p0[0]=f2bf(e0.x); p0[1]=f2bf(e0.y); p0[2]=f2bf(e0.z); p0[3]=f2bf(e0.w);
      p0[4]=f2bf(e1.x); p0[5]=f2bf(e1.y); p0[6]=f2bf(e1.z); p0[7]=f2bf(e1.w);
      p1[0]=f2bf(e2.x); p1[1]=f2bf(e2.y); p1[2]=f2bf(e2.z); p1[3]=f2bf(e2.w);
      p1[4]=f2bf(e3.x); p1[5]=f2bf(e3.y); p1[6]=f2bf(e3.z); p1[7]=f2bf(e3.w);
      *(short8*)&lA[rl * KP1 + f * 16]     = p0;
      *(short8*)&lA[rl * KP1 + f * 16 + 8] = p1;
    }
    // reduce across the 8 lanes of this row (lane bits 0..2)
#pragma unroll
    for (int d = 0; d < 16; d++) {
      se[d] += __shfl_xor(se[d], 1, 64);
      se[d] += __shfl_xor(se[d], 2, 64);
      se[d] += __shfl_xor(se[d], 4, 64);
    }
    sumsq += __shfl_xor(sumsq, 1, 64);
    sumsq += __shfl_xor(sumsq, 2, 64);
    sumsq += __shfl_xor(sumsq, 4, 64);
    fm1   += __shfl_xor(fm1, 1, 64);
    fm1   += __shfl_xor(fm1, 2, 64);
    fm1   += __shfl_xor(fm1, 4, 64);

    if (q == 0) {
      float s2 = 0.f;
#pragma unroll
      for (int d = 0; d < 16; d++) s2 += se[d] * se[d];
      float fm2 = 0.5f * (s2 - sumsq);
      float fmc = bc[0];
      short tail[32];
#pragma unroll
      for (int i = 0; i < NCONT; i++) {
        float c = cont[(size_t)b * NCONT + i];
        fmc += c * Wc[i];
        tail[i] = f2bf(c);
      }
#pragma unroll
      for (int i = NCONT; i < 32; i++) tail[i] = 0;
#pragma unroll
      for (int v = 0; v < 4; v++) {
        short8 tv;
#pragma unroll
        for (int e = 0; e < 8; e++) tv[e] = tail[v * 8 + e];
        *(short8*)&lA[rl * KP1 + 416 + v * 8] = tv;
      }
      out[b] = (fm1 + fmc + fm2) * Wout[0] + bout[0];
    }
  }
  __syncthreads();

  // ===== MFMA phases: wave covers all 32 rows x its 128-col stripe =====
  const int lane = tid & 63;
  const int wave = tid >> 6;
  const int lrow = lane & 15;
  const int quad = lane >> 4;
  const int wn   = wave * 128;
  const int kq   = quad * 8;
  f32x4 acc[2][8];

  // ----- layer 1: h1 = relu(dnn @ W1 + b1) -----
#pragma unroll
  for (int i = 0; i < 2; i++)
#pragma unroll
    for (int j = 0; j < 8; j++)
#pragma unroll
      for (int r = 0; r < 4; r++) acc[i][j][r] = 0.f;
  {
    const short* wp[8];
#pragma unroll
    for (int j = 0; j < 8; j++)
      wp[j] = W1T + (size_t)(wn + j * 16 + lrow) * K1 + kq;
    bf16x8 wf[2][8], af[2][2];
#pragma unroll
    for (int j = 0; j < 8; j++) wf[0][j] = *(const bf16x8*)(wp[j]);
#pragma unroll
    for (int i = 0; i < 2; i++) af[0][i] = *(const bf16x8*)&lA[(i * 16 + lrow) * KP1 + kq];
#pragma unroll
    for (int ks = 0; ks < K1 / 32; ks++) {
      const int cur = ks & 1, nxt = cur ^ 1;
      if (ks + 1 < K1 / 32) {
#pragma unroll
        for (int j = 0; j < 8; j++) wf[nxt][j] = *(const bf16x8*)(wp[j] + (ks + 1) * 32);
#pragma unroll
        for (int i = 0; i < 2; i++)
          af[nxt][i] = *(const bf16x8*)&lA[(i * 16 + lrow) * KP1 + (ks + 1) * 32 + kq];
      }
#pragma unroll
      for (int i = 0; i < 2; i++)
#pragma unroll
        for (int j = 0; j < 8; j++)
          acc[i][j] = __builtin_amdgcn_mfma_f32_16x16x32_bf16(af[cur][i], wf[cur][j], acc[i][j], 0, 0, 0);
    }
  }
  // epilogue 1: bias+relu -> bf16 h1 tile (cols >= NH forced to 0)
#pragma unroll
  for (int j = 0; j < 8; j++) {
    int col = wn + j * 16 + lrow;
    if (col < K2) {
      float bias = (col < NH) ? b1[col] : 0.f;
#pragma unroll
      for (int i = 0; i < 2; i++)
#pragma unroll
        for (int r = 0; r < 4; r++) {
          int row = i * 16 + quad * 4 + r;
          float v = (col < NH) ? fmaxf(acc[i][j][r] + bias, 0.f) : 0.f;
          lH[row * KP2 + col] = f2bf(v);
        }
    }
  }
  __syncthreads();

  // ----- layer 2: h2 = relu(h1 @ W2 + b2), fused dot with Wout -----
#pragma unroll
  for (int i = 0; i < 2; i++)
#pragma unroll
    for (int j = 0; j < 8; j++)
#pragma unroll
      for (int r = 0; r < 4; r++) acc[i][j][r] = 0.f;
  {
    const short* wp[8];
#pragma unroll
    for (int j = 0; j < 8; j++)
      wp[j] = W2T + (size_t)(wn + j * 16 + lrow) * K2 + kq;
    bf16x8 wf[2][8], af[2][2];
#pragma unroll
    for (int j = 0; j < 8; j++) wf[0][j] = *(const bf16x8*)(wp[j]);
#pragma unroll
    for (int i = 0; i < 2; i++) af[0][i] = *(const bf16x8*)&lH[(i * 16 + lrow) * KP2 + kq];
#pragma unroll
    for (int ks = 0; ks < K2 / 32; ks++) {
      const int cur = ks & 1, nxt = cur ^ 1;
      if (ks + 1 < K2 / 32) {
#pragma unroll
        for (int j = 0; j < 8; j++) wf[nxt][j] = *(const bf16x8*)(wp[j] + (ks + 1) * 32);
#pragma unroll
        for (int i = 0; i < 2; i++)
          af[nxt][i] = *(const bf16x8*)&lH[(i * 16 + lrow) * KP2 + (ks + 1) * 32 + kq];
      }
#pragma unroll
      for (int i = 0; i < 2; i++)
#pragma unroll
        for (int j = 0; j < 8; j++)
          acc[i][j] = __builtin_amdgcn_mfma_f32_16x16x32_bf16(af[cur][i], wf[cur][j], acc[i][j], 0, 0, 0);
    }
  }
  // epilogue 2: relu + dot with Wout[1:], reduce, atomicAdd into out
  {
    float bw[8], wo[8];
#pragma unroll
    for (int j = 0; j < 8; j++) {
      int col = wn + j * 16 + lrow;
      bw[j] = (col < NH) ? b2[col] : 0.f;
      wo[j] = (col < NH) ? Wout[1 + col] : 0.f;
    }
#pragma unroll
    for (int i = 0; i < 2; i++) {
#pragma unroll
      for (int r = 0; r < 4; r++) {
        float s = 0.f;
#pragma unroll
        for (int j = 0; j < 8; j++)
          s += fmaxf(acc[i][j][r] + bw[j], 0.f) * wo[j];   // pad cols: acc=0,bw=0,wo=0
        s += __shfl_xor(s, 1, 64);
        s += __shfl_xor(s, 2, 64);
        s += __shfl_xor(s, 4, 64);
        s += __shfl_xor(s, 8, 64);
        if (lrow == 0) atomicAdd(&out[bm + i * 16 + quad * 4 + r], s);
      }
    }
  }
}

extern "C" void kernel_launch(void* const* d_in, const int* in_sizes, int n_in,
                              void* d_out, int out_size, void* d_ws, size_t ws_size,
                              hipStream_t stream) {
  const float* cont   = (const float*)d_in[0];
  const int*   cat    = (const int*)d_in[1];
  const float* W_cont = (const float*)d_in[2];
  const float* b_cont = (const float*)d_in[3];
  const float* emb1   = (const float*)d_in[4];
  const float* emb    = (const float*)d_in[5];
  const float* W1     = (const float*)d_in[6];
  const float* b1     = (const float*)d_in[7];
  const float* W2     = (const float*)d_in[8];
  const float* b2     = (const float*)d_in[9];
  const float* W_out  = (const float*)d_in[10];
  const float* b_out  = (const float*)d_in[11];
  float* out = (float*)d_out;

  char* ws = (char*)d_ws;
  short* W1T = (short*)ws;                              // 512*448*2 = 458752 B
  short* W2T = (short*)(ws + (size_t)NPAD * K1 * 2);    // 512*416*2 = 425984 B
  (void)ws_size; (void)in_sizes; (void)n_in; (void)out_size;

  prep_k<<<dim3((NPAD * K1 + NPAD * K2) / 256), dim3(256), 0, stream>>>(W1, W2, W1T, W2T);
  fused_k<<<dim3(NB / ROWS), dim3(256), 0, stream>>>(cont, cat, W_cont, b_cont,
                                                     emb1, emb, W1T, b1, W2T, b2,
                                                     W_out, b_out, out);
}